// Round 17
// baseline (93.023 us; speedup 1.0000x reference)
//
#include <hip/hip_runtime.h>
#include <hip/hip_bf16.h>

// VQ-VAE vector quantizer, MI355X — pipelined ct-loop, 4 blocks/CU.
// [k_prep] 64 blocks: emb -> PLAIN fp8 E (x512) + cn=||e||^2 fp32; loss=0
// [k_main] 1024 blocks x 256thr (4/CU): block = 32 hw rows of one b.
//   - A: coalesced lat -> fp32 LDS transpose -> fp8 swizzled A-tile (4KB) + rn
//   - ct-loop over 8 E-tiles (16KB fp8), double-buffered, ONE barrier/iter:
//     compute(cur) || ds_write(next, loaded last iter) || issue L2 loads(next2)
//   - per wave/ct: codes [w*32,+32): 8 ds_read_b64 -> 16 MFMA (4 acc chains),
//     fp32 fold s = cn - (2/512)t, running argmin in regs
//   - butterfly over l15 -> ms/mi[4][32] -> 4-way merge -> win
//   - gather q=emb[k*] fp32 -> [B,D,H,W], one loss atomicAdd per block

typedef __attribute__((ext_vector_type(4))) float f32x4;

// workspace layout (bytes)
#define WS_E 0u          // fp8 PLAIN [1024][128] = 131072
#define WS_C 131072u     // f32 cn[1024]          = 4096

#define LOSS_SCALE (1.25f / 4194304.0f)
#define NEG2_INV_LAMBDA (-2.0f / 512.0f)

static __device__ inline unsigned cvt4_fp8(float a, float b, float c, float d) {
    int v = __builtin_amdgcn_cvt_pk_fp8_f32(a, b, 0, false);
    v = __builtin_amdgcn_cvt_pk_fp8_f32(c, d, v, true);
    return (unsigned)v;
}

// ---------------- codebook prep (PLAIN layout) ----------------
__global__ __launch_bounds__(256) void k_prep(const float* __restrict__ emb,
                                              char* __restrict__ Eb,
                                              float* __restrict__ cn,
                                              float* __restrict__ loss) {
    const int t = threadIdx.x;
    const int row = (blockIdx.x << 4) + (t >> 4), c = t & 15;
    const float4* ep = (const float4*)(emb + ((size_t)row << 7) + (c << 3));
    float4 e0 = ep[0], e1 = ep[1];
    float s = e0.x*e0.x + e0.y*e0.y + e0.z*e0.z + e0.w*e0.w
            + e1.x*e1.x + e1.y*e1.y + e1.z*e1.z + e1.w*e1.w;
#pragma unroll
    for (int m = 1; m < 16; m <<= 1) s += __shfl_xor(s, m);
    if (c == 0) cn[row] = s;
    uint2 v;
    v.x = cvt4_fp8(512.f*e0.x, 512.f*e0.y, 512.f*e0.z, 512.f*e0.w);
    v.y = cvt4_fp8(512.f*e1.x, 512.f*e1.y, 512.f*e1.z, 512.f*e1.w);
    *(uint2*)(Eb + row * 128 + c * 8) = v;
    if (blockIdx.x == 0 && t == 0) loss[0] = 0.f;
}

// ---------------- main: pipelined scoring ----------------
// LDS: buf0 @0 (16K) | buf1 @16384 (16K, Tf overlay) | A @32768 (4K) |
//      ms @36864 (512) | mi @37376 (512) | win @37888 (128) | rs @38016 (16)
//      = 38032 B -> 4 blocks/CU.
__global__ __launch_bounds__(256, 4) void k_main(const float* __restrict__ lat,
                                                 const float* __restrict__ emb,
                                                 const char* __restrict__ Eb,
                                                 const float* __restrict__ cn,
                                                 float* __restrict__ outq,
                                                 float* __restrict__ loss) {
    __shared__ __align__(16) char lds[38048];
    char*  A   = lds + 32768;
    float* Tf  = (float*)(lds + 16384);
    float* ms  = (float*)(lds + 36864);
    int*   mi  = (int*)  (lds + 37376);
    int*   win = (int*)  (lds + 37888);
    float* rs  = (float*)(lds + 38016);

    const int t = threadIdx.x, bm = blockIdx.x;   // 1024 blocks
    const int lane = t & 63, w = t >> 6;          // 4 waves
    const int l15 = lane & 15, lg = lane >> 4;
    const int b = bm >> 5, hw0 = (bm & 31) << 5;  // 32 rows

    // ---- prologue: issue E tile 0,1 loads (L2) ----
    uint4 e0[4], e1[4];
#pragma unroll
    for (int j = 0; j < 4; ++j) e0[j] = *(const uint4*)(Eb + t * 64 + j * 16);
#pragma unroll
    for (int j = 0; j < 4; ++j) e1[j] = *(const uint4*)(Eb + 16384 + t * 64 + j * 16);

    // ---- lat -> Tf (coalesced float4, col-swizzled) ----
    const float* latp = lat + ((size_t)b << 17) + hw0;
#pragma unroll
    for (int i = 0; i < 4; ++i) {
        int idx = i * 256 + t;
        int d = idx >> 3, hw4 = (idx & 7) << 2;
        float4 v = *(const float4*)(latp + ((size_t)d << 10) + hw4);
        *(float4*)(&Tf[(d << 5) + (hw4 ^ (((d >> 3) & 7) << 2))]) = v;
    }
    __syncthreads();

    // ---- stage tile 0 into buf0 (regs arrived long ago) ----
#pragma unroll
    for (int j = 0; j < 4; ++j) {
        int goff = t * 64 + j * 16;
        int row = goff >> 7, c16 = (goff >> 4) & 7;
        *(uint4*)(lds + row * 128 + ((c16 << 4) ^ ((row & 7) << 4))) = e0[j];
    }

    // ---- Tf columns -> fp8 A-tile (swz) + row norms ----
    float rn = 0.f;
    {
        const int rowl = t & 31, c8 = t >> 5;
        float q[16];
#pragma unroll
        for (int jj = 0; jj < 16; ++jj) {
            int d = c8 * 16 + jj;
            q[jj] = Tf[(d << 5) + (rowl ^ (((d >> 3) & 7) << 2))];
            rn = fmaf(q[jj], q[jj], rn);
        }
        uint4 wv;
        wv.x = cvt4_fp8(q[0],  q[1],  q[2],  q[3]);
        wv.y = cvt4_fp8(q[4],  q[5],  q[6],  q[7]);
        wv.z = cvt4_fp8(q[8],  q[9],  q[10], q[11]);
        wv.w = cvt4_fp8(q[12], q[13], q[14], q[15]);
        *(uint4*)(A + rowl * 128 + ((c8 * 16) ^ ((rowl & 7) << 4))) = wv;
    }
#pragma unroll
    for (int m = 1; m < 64; m <<= 1) rn += __shfl_xor(rn, m);
    if (lane == 0) rs[w] = rn;
    __syncthreads();   // A + buf0 ready; Tf dead

    // ---- A-frags once into regs ----
    long av[2][4];
#pragma unroll
    for (int m = 0; m < 2; ++m)
#pragma unroll
        for (int ks = 0; ks < 4; ++ks) {
            int r = m * 16 + l15;
            av[m][ks] = *(const long*)(A + r * 128 + ((ks * 32 + lg * 8) ^ ((r & 7) << 4)));
        }

    float run_s[2][4]; int run_i[2][4];
#pragma unroll
    for (int m = 0; m < 2; ++m)
#pragma unroll
        for (int r = 0; r < 4; ++r) { run_s[m][r] = 3.0e38f; run_i[m][r] = 0; }

    // ---- pipelined ct-loop: ONE barrier per iter ----
#pragma unroll
    for (int ct = 0; ct < 8; ++ct) {
        char* cbuf = lds + ((ct & 1) << 14);
        const int kb = (ct << 7) + (w << 5);
        float cv0 = cn[kb + l15];
        float cv1 = cn[kb + 16 + l15];

        if (ct < 6) {   // issue loads for tile ct+2 into the now-free reg set
            if ((ct & 1) == 0) {
#pragma unroll
                for (int j = 0; j < 4; ++j)
                    e0[j] = *(const uint4*)(Eb + (ct + 2) * 16384 + t * 64 + j * 16);
            } else {
#pragma unroll
                for (int j = 0; j < 4; ++j)
                    e1[j] = *(const uint4*)(Eb + (ct + 2) * 16384 + t * 64 + j * 16);
            }
        }

        f32x4 acc[2][2];
#pragma unroll
        for (int m = 0; m < 2; ++m)
#pragma unroll
            for (int c = 0; c < 2; ++c) acc[m][c] = (f32x4){0.f, 0.f, 0.f, 0.f};
#pragma unroll
        for (int ks = 0; ks < 4; ++ks) {
            long bv[2];
#pragma unroll
            for (int c = 0; c < 2; ++c) {
                int rl = (w << 5) + (c << 4) + l15;
                bv[c] = *(const long*)(cbuf + rl * 128 +
                         ((ks * 32 + lg * 8) ^ ((rl & 7) << 4)));
            }
#pragma unroll
            for (int m = 0; m < 2; ++m)
#pragma unroll
                for (int c = 0; c < 2; ++c)
                    acc[m][c] = __builtin_amdgcn_mfma_f32_16x16x32_fp8_fp8(av[m][ks], bv[c], acc[m][c], 0, 0, 0);
        }

#pragma unroll
        for (int c = 0; c < 2; ++c) {
            const int kg = kb + (c << 4) + l15;
            const float cv = c ? cv1 : cv0;
#pragma unroll
            for (int m = 0; m < 2; ++m)
#pragma unroll
                for (int r = 0; r < 4; ++r) {
                    float s = fmaf(NEG2_INV_LAMBDA, acc[m][c][r], cv);
                    if (s < run_s[m][r]) { run_s[m][r] = s; run_i[m][r] = kg; }
                }
        }

        if (ct < 7) {   // write tile ct+1 (loaded a full iter ago) into other buf
            char* obuf = lds + (((ct + 1) & 1) << 14);
            if (((ct + 1) & 1) == 0) {
#pragma unroll
                for (int j = 0; j < 4; ++j) {
                    int goff = t * 64 + j * 16;
                    int row = goff >> 7, c16 = (goff >> 4) & 7;
                    *(uint4*)(obuf + row * 128 + ((c16 << 4) ^ ((row & 7) << 4))) = e0[j];
                }
            } else {
#pragma unroll
                for (int j = 0; j < 4; ++j) {
                    int goff = t * 64 + j * 16;
                    int row = goff >> 7, c16 = (goff >> 4) & 7;
                    *(uint4*)(obuf + row * 128 + ((c16 << 4) ^ ((row & 7) << 4))) = e1[j];
                }
            }
        }
        __syncthreads();
    }

    // ---- butterfly over the 16 code-lanes; per-wave winners ----
#pragma unroll
    for (int m = 0; m < 2; ++m)
#pragma unroll
        for (int r = 0; r < 4; ++r) {
            float s = run_s[m][r]; int bi = run_i[m][r];
#pragma unroll
            for (int mask = 1; mask < 16; mask <<= 1) {
                float os = __shfl_xor(s, mask);
                int   oi = __shfl_xor(bi, mask);
                if (os < s || (os == s && oi < bi)) { s = os; bi = oi; }
            }
            if (l15 == 0) {
                int row = m * 16 + (lg << 2) + r;      // 0..31
                ms[(w << 5) + row] = s;
                mi[(w << 5) + row] = bi;
            }
        }
    __syncthreads();

    // ---- wave 0: 4-way merge + win + loss ----
    if (w == 0) {
        float bs = 0.f;
        if (lane < 32) {
            bs = ms[lane]; int bi = mi[lane];
#pragma unroll
            for (int w2 = 1; w2 < 4; ++w2) {
                float s2 = ms[(w2 << 5) + lane]; int i2 = mi[(w2 << 5) + lane];
                if (s2 < bs || (s2 == bs && i2 < bi)) { bs = s2; bi = i2; }
            }
            win[lane] = bi;
        }
        float v = (lane < 32) ? bs : 0.f;
        if (lane < 4) v += rs[lane];
#pragma unroll
        for (int m = 1; m < 64; m <<= 1) v += __shfl_xor(v, m);
        if (lane == 0) atomicAdd(loss, v * LOSS_SCALE);
    }
    __syncthreads();

    // ---- gather q = emb[k*] fp32, store [B,D,H,W] coalesced ----
    {
        const int rowl = t & 31, dg = t >> 5;      // 8 dgrps x 16 d
        const int bi = win[rowl];
        const float4* eg = (const float4*)(emb + ((size_t)bi << 7) + (dg << 4));
        float* ob = outq + ((size_t)b << 17) + ((size_t)(dg << 4) << 10) + hw0 + rowl;
#pragma unroll
        for (int jj = 0; jj < 4; ++jj) {
            float4 v = eg[jj];
            ob[(size_t)(jj * 4 + 0) << 10] = v.x;
            ob[(size_t)(jj * 4 + 1) << 10] = v.y;
            ob[(size_t)(jj * 4 + 2) << 10] = v.z;
            ob[(size_t)(jj * 4 + 3) << 10] = v.w;
        }
    }
}

extern "C" void kernel_launch(void* const* d_in, const int* in_sizes, int n_in,
                              void* d_out, int out_size, void* d_ws, size_t ws_size,
                              hipStream_t stream) {
    const float* lat = (const float*)d_in[0];   // [32,128,32,32]
    const float* emb = (const float*)d_in[1];   // [1024,128]
    float* out = (float*)d_out;                 // q (4194304) + vq_loss (1)
    char* ws = (char*)d_ws;
    char*  E    = ws + WS_E;
    float* cn   = (float*)(ws + WS_C);
    float* loss = out + 4194304;

    k_prep<<<64,   256, 0, stream>>>(emb, E, cn, loss);
    k_main<<<1024, 256, 0, stream>>>(lat, emb, E, cn, out, loss);
}

// Round 18
// 42.725 us; speedup vs baseline: 2.1773x; 2.1773x over previous
//
#include <hip/hip_runtime.h>
#include <hip/hip_bf16.h>

// VQ-VAE vector quantizer, MI355X — half-codebook blocks, 2/CU, atomicMin merge.
// [memset] pk[32768] u64 = 0xFF
// [k_prep] 64 blocks: emb -> PLAIN fp8 E (x512) + cn=||e||^2 fp32; loss=0
// [k_main] 512 blocks x 512thr (2/CU): block (rowgrp=bm>>1, half=bm&1) =
//          128 rows x 512 codes. lat HBM loads first; E-half (64KB) reg-staged
//          from L2 w/ swizzle-at-write; A-frags in regs; phase B = 4 ct tiles;
//          butterfly -> monotone-pack -> atomicMin64(pk[row]); rn loss (half 0).
// [k_out]  512 blocks: unpack winners, sum s* -> loss, gather q -> [B,D,H,W].

typedef __attribute__((ext_vector_type(4))) float f32x4;

// workspace layout (bytes)
#define WS_E  0u          // fp8 PLAIN [1024][128] = 131072
#define WS_C  131072u     // f32 cn[1024]          = 4096
#define WS_PK 135168u     // u64 pk[32768]         = 262144

#define LOSS_SCALE (1.25f / 4194304.0f)
#define NEG2_INV_LAMBDA (-2.0f / 512.0f)

static __device__ inline unsigned cvt4_fp8(float a, float b, float c, float d) {
    int v = __builtin_amdgcn_cvt_pk_fp8_f32(a, b, 0, false);
    v = __builtin_amdgcn_cvt_pk_fp8_f32(c, d, v, true);
    return (unsigned)v;
}

// ---------------- codebook prep (PLAIN layout) ----------------
__global__ __launch_bounds__(256) void k_prep(const float* __restrict__ emb,
                                              char* __restrict__ Eb,
                                              float* __restrict__ cn,
                                              float* __restrict__ loss) {
    const int t = threadIdx.x;
    const int row = (blockIdx.x << 4) + (t >> 4), c = t & 15;
    const float4* ep = (const float4*)(emb + ((size_t)row << 7) + (c << 3));
    float4 e0 = ep[0], e1 = ep[1];
    float s = e0.x*e0.x + e0.y*e0.y + e0.z*e0.z + e0.w*e0.w
            + e1.x*e1.x + e1.y*e1.y + e1.z*e1.z + e1.w*e1.w;
#pragma unroll
    for (int m = 1; m < 16; m <<= 1) s += __shfl_xor(s, m);
    if (c == 0) cn[row] = s;
    uint2 v;
    v.x = cvt4_fp8(512.f*e0.x, 512.f*e0.y, 512.f*e0.z, 512.f*e0.w);
    v.y = cvt4_fp8(512.f*e1.x, 512.f*e1.y, 512.f*e1.z, 512.f*e1.w);
    *(uint2*)(Eb + row * 128 + c * 8) = v;
    if (blockIdx.x == 0 && t == 0) loss[0] = 0.f;
}

// ---------------- main: half-codebook scoring ----------------
// LDS: E-half @0 (64K, swz) | C @65536 (2K) | rs @67584 (32) = 67616 B -> 2/CU.
__global__ __launch_bounds__(512, 2) void k_main(const float* __restrict__ lat,
                                                 const char* __restrict__ Eb,
                                                 const float* __restrict__ cn,
                                                 unsigned long long* __restrict__ pk,
                                                 float* __restrict__ loss) {
    __shared__ __align__(16) char lds[67616];
    char*  ldsE = lds;                        // fp8 swz [512][128]
    float* ldsC = (float*)(lds + 65536);      // [512]
    float* rs   = (float*)(lds + 67584);      // [8]

    const int t = threadIdx.x, bm = blockIdx.x;      // 512 blocks
    const int lane = t & 63, w = t >> 6;             // 8 waves
    const int l15 = lane & 15, lg = lane >> 4;
    const int rowgrp = bm >> 1, half = bm & 1;
    const int b = rowgrp >> 3, hw0 = (rowgrp & 7) << 7;

    // ---- lat loads FIRST (HBM, longest latency) ----
    const float* lp = lat + ((size_t)b << 17) + hw0 + (w << 4) + l15;
    float xv[4][8];
#pragma unroll
    for (int ks = 0; ks < 4; ++ks)
#pragma unroll
        for (int j = 0; j < 8; ++j)
            xv[ks][j] = lp[(size_t)(ks * 32 + lg * 8 + j) << 10];

    // ---- stage E-half from L2 (interleaved load -> swizzled ds_write) ----
    const char* Eh = Eb + (half << 16);
#pragma unroll
    for (int i = 0; i < 8; ++i) {
        int goff = (i << 13) + t * 16;
        uint4 u = *(const uint4*)(Eh + goff);
        int row = goff >> 7, c16 = (goff >> 4) & 7;
        *(uint4*)(ldsE + row * 128 + ((c16 << 4) ^ ((row & 7) << 4))) = u;
    }
    if (t < 128) {
        float4 cv = *(const float4*)(cn + (half << 9) + (t << 2));
        *(float4*)(ldsC + (t << 2)) = cv;
    }

    // ---- A-frags + row norms ----
    float rn = 0.f;
    long av[4];
#pragma unroll
    for (int ks = 0; ks < 4; ++ks) {
#pragma unroll
        for (int j = 0; j < 8; ++j) rn = fmaf(xv[ks][j], xv[ks][j], rn);
        unsigned lo = cvt4_fp8(xv[ks][0], xv[ks][1], xv[ks][2], xv[ks][3]);
        unsigned hi = cvt4_fp8(xv[ks][4], xv[ks][5], xv[ks][6], xv[ks][7]);
        av[ks] = (long)(((unsigned long long)hi << 32) | lo);
    }
    __syncthreads();                 // E-half + cn resident

    // ---- phase B: wave owns 16 rows, sweeps this half's 512 codes ----
    float run_s[4]; int run_i[4];
#pragma unroll
    for (int r = 0; r < 4; ++r) { run_s[r] = 3.0e38f; run_i[r] = 0; }

    for (int ct = 0; ct < 4; ++ct) {
        float cnv[8];
#pragma unroll
        for (int c = 0; c < 8; ++c) cnv[c] = ldsC[(ct << 7) + (c << 4) + l15];

        f32x4 acc[8];
#pragma unroll
        for (int c = 0; c < 8; ++c) acc[c] = (f32x4){0.f, 0.f, 0.f, 0.f};
#pragma unroll
        for (int ks = 0; ks < 4; ++ks) {
            long bv[8];
#pragma unroll
            for (int c = 0; c < 8; ++c) {
                int rr = (ct << 7) + (c << 4) + l15;
                bv[c] = *(const long*)(ldsE + rr * 128 +
                         ((ks * 32 + lg * 8) ^ ((rr & 7) << 4)));
            }
#pragma unroll
            for (int c = 0; c < 8; ++c)
                acc[c] = __builtin_amdgcn_mfma_f32_16x16x32_fp8_fp8(av[ks], bv[c], acc[c], 0, 0, 0);
        }
#pragma unroll
        for (int c = 0; c < 8; ++c) {
            int kg = (half << 9) + (ct << 7) + (c << 4) + l15;
#pragma unroll
            for (int r = 0; r < 4; ++r) {
                float s = fmaf(NEG2_INV_LAMBDA, acc[c][r], cnv[c]);
                if (s < run_s[r]) { run_s[r] = s; run_i[r] = kg; }
            }
        }
    }

    // ---- butterfly over 16 code-lanes; pack; atomicMin64 merge ----
#pragma unroll
    for (int r = 0; r < 4; ++r) {
        float s = run_s[r]; int bi = run_i[r];
#pragma unroll
        for (int mask = 1; mask < 16; mask <<= 1) {
            float os = __shfl_xor(s, mask);
            int   oi = __shfl_xor(bi, mask);
            if (os < s || (os == s && oi < bi)) { s = os; bi = oi; }
        }
        if (l15 == 0) {
            int row = (w << 4) + (lg << 2) + r;            // 0..127
            int grow = (rowgrp << 7) + row;
            unsigned u = __float_as_uint(s);
            unsigned mm = (u & 0x80000000u) ? ~u : (u | 0x80000000u);
            unsigned long long pkv = (((unsigned long long)mm) << 32) | (unsigned)bi;
            atomicMin(&pk[grow], pkv);
        }
    }

    // ---- rn loss partial (half 0 blocks cover each x^2 once) ----
    if (half == 0) {
#pragma unroll
        for (int m = 1; m < 64; m <<= 1) rn += __shfl_xor(rn, m);
        if (lane == 0) rs[w] = rn;
        __syncthreads();
        if (t == 0) {
            float v = rs[0] + rs[1] + rs[2] + rs[3] + rs[4] + rs[5] + rs[6] + rs[7];
            atomicAdd(loss, v * LOSS_SCALE);
        }
    }
}

// ---------------- output: gather + loss ----------------
__global__ __launch_bounds__(256) void k_out(const unsigned long long* __restrict__ pk,
                                             const float* __restrict__ emb,
                                             float* __restrict__ outq,
                                             float* __restrict__ loss) {
    __shared__ int win[64];
    const int t = threadIdx.x, bm = blockIdx.x;
    const int b = bm >> 4, hw0 = (bm & 15) << 6;
    const int n0 = bm << 6;

    if (t < 64) {                                   // wave 0: winners + sum(s*)
        unsigned long long p = pk[n0 + t];
        win[t] = (int)(unsigned)(p & 0xFFFFFFFFull);
        unsigned mm = (unsigned)(p >> 32);
        unsigned u = (mm & 0x80000000u) ? (mm ^ 0x80000000u) : ~mm;
        float s = __uint_as_float(u);
#pragma unroll
        for (int m = 1; m < 64; m <<= 1) s += __shfl_xor(s, m);
        if (t == 0) atomicAdd(loss, s * LOSS_SCALE);
    }
    __syncthreads();

    {   // gather q = emb[k*] fp32, store [B,D,H,W] (64-lane 256B segments)
        const int row = t & 63, dg = t >> 6;        // 4 dgrps x 32 d
        const int bi = win[row];
        const float4* eg = (const float4*)(emb + ((size_t)bi << 7) + (dg << 5));
        float* ob = outq + ((size_t)b << 17) + ((size_t)(dg << 5) << 10) + hw0 + row;
#pragma unroll
        for (int jj = 0; jj < 8; ++jj) {
            float4 v = eg[jj];
            ob[(size_t)(jj * 4 + 0) << 10] = v.x;
            ob[(size_t)(jj * 4 + 1) << 10] = v.y;
            ob[(size_t)(jj * 4 + 2) << 10] = v.z;
            ob[(size_t)(jj * 4 + 3) << 10] = v.w;
        }
    }
}

extern "C" void kernel_launch(void* const* d_in, const int* in_sizes, int n_in,
                              void* d_out, int out_size, void* d_ws, size_t ws_size,
                              hipStream_t stream) {
    const float* lat = (const float*)d_in[0];   // [32,128,32,32]
    const float* emb = (const float*)d_in[1];   // [1024,128]
    float* out = (float*)d_out;                 // q (4194304) + vq_loss (1)
    char* ws = (char*)d_ws;
    char*  E    = ws + WS_E;
    float* cn   = (float*)(ws + WS_C);
    unsigned long long* pk = (unsigned long long*)(ws + WS_PK);
    float* loss = out + 4194304;

    hipMemsetAsync(ws + WS_PK, 0xFF, 262144, stream);
    k_prep<<<64,  256, 0, stream>>>(emb, E, cn, loss);
    k_main<<<512, 512, 0, stream>>>(lat, E, cn, pk, loss);
    k_out <<<512, 256, 0, stream>>>(pk, emb, out, loss);
}